// Round 4
// baseline (4786.432 us; speedup 1.0000x reference)
//
#include <hip/hip_runtime.h>
#include <cmath>

#define TT   6
#define NB   128
#define NHD  6
#define HD   32
#define HWN  64
#define DIM  192
#define SCALE 0.17677669529663687f

typedef __attribute__((ext_vector_type(8))) short v8s;
typedef __attribute__((ext_vector_type(4))) float v4f;

__device__ __forceinline__ short f2bf(float f) {
  union { float f; unsigned u; } v; v.f = f;
  unsigned r = v.u + 0x7fffu + ((v.u >> 16) & 1u);
  return (short)(r >> 16);
}

// ---- converter: fp32 -> bf16 (weights only; biases stay fp32) ----
__global__ void cvt_kernel(const float* __restrict__ src, short* __restrict__ dst, int n4) {
  int idx = blockIdx.x * 256 + threadIdx.x;
  if (idx >= n4) return;
  const float* s = src + idx * 4;
  short4 r;
  r.x = f2bf(s[0]); r.y = f2bf(s[1]); r.z = f2bf(s[2]); r.w = f2bf(s[3]);
  *(short4*)(dst + idx * 4) = r;
}

// One block per (i, b). No inter-kernel activations: everything from x + weights.
// LDS (94.2 KB): posy/posx fp32 tables; KQ = K_j (rows, stride 200, aliased as Q_i
// at start); Vt = V_j^T (stride 72); SX = per-wave 16x192 strip (o/y1n/h), aliased
// block-wide as the (x+pos) staging tile; Pl = per-wave P strip (stride 72).
__global__ __launch_bounds__(256) void fused_all(
    const float* __restrict__ x,
    const short* __restrict__ Wqkv_bf,
    const short* __restrict__ Wproj_bf,
    const short* __restrict__ W1_bf,
    const short* __restrict__ W2_bf,
    const float* __restrict__ bproj, const float* __restrict__ gamma,
    const float* __restrict__ beta, const float* __restrict__ b1,
    const float* __restrict__ b2,
    float* __restrict__ out) {
  __shared__ float posy[8 * 96];
  __shared__ float posx[8 * 96];
  __shared__ short KQ[64 * 200];
  __shared__ short Vt[DIM * 72];
  __shared__ short SX[4][16 * 200];
  __shared__ short Pl[4][16 * 72];

  int i = blockIdx.x, b = blockIdx.y;
  int tid = threadIdx.x, w = tid >> 6, lane = tid & 63;
  int l15 = lane & 15, quad = lane >> 4;
  const v4f vzero = {0.f, 0.f, 0.f, 0.f};
  short* xp = &SX[0][0];   // 64 rows x 192 cols, stride 200 (aliases all strips)

  // ---- sine position tables (reference formula; separable in (y|x, c)) ----
  for (int idx = tid; idx < 1536; idx += 256) {
    int hx = idx / 768;
    int rem = idx - hx * 768;
    int rr = rem / 96, c = rem - rr * 96;
    int m = c >> 1;
    float embed = (float)(rr + 1) * (6.283185307179586f / 8.000001f);
    float dt = powf(10000.0f, (float)m * (1.0f / 48.0f));
    float ang = embed / dt;
    float v = (c & 1) ? cosf(ang) : sinf(ang);
    (hx ? posx : posy)[rr * 96 + c] = v;
  }

  auto stage_frame = [&](int t) {   // xp = bf16(x[b, frame t] + pos)
    const float* xrow = x + (size_t)(b * (TT * HWN) + t * HWN) * DIM;
    for (int c = tid; c < HWN * 24; c += 256) {
      int row = c / 24, col8 = (c - (c / 24) * 24) * 8;
      const float* xs = xrow + row * DIM + col8;
      const float* pp = (col8 < 96) ? (posy + (row >> 3) * 96 + col8)
                                    : (posx + (row & 7) * 96 + (col8 - 96));
      v8s r;
#pragma unroll
      for (int jj = 0; jj < 8; jj++) r[jj] = f2bf(xs[jj] + pp[jj]);
      *(v8s*)(xp + row * 200 + col8) = r;
    }
  };

  // ---- Q_i = (x_i + pos) @ Wq^T * SCALE  (C-layout -> KQ -> A-frags) ----
  stage_frame(i);
  __syncthreads();
  {
    v4f qacc[12];
#pragma unroll
    for (int ct = 0; ct < 12; ct++) qacc[ct] = vzero;
#pragma unroll
    for (int ks = 0; ks < 6; ks++) {
      v8s a = *(const v8s*)(xp + (w * 16 + l15) * 200 + ks * 32 + quad * 8);
#pragma unroll
      for (int ct = 0; ct < 12; ct++) {
        v8s bf = *(const v8s*)(Wqkv_bf + (size_t)(ct * 16 + l15) * DIM + ks * 32 + quad * 8);
        qacc[ct] = __builtin_amdgcn_mfma_f32_16x16x32_bf16(a, bf, qacc[ct], 0, 0, 0);
      }
    }
#pragma unroll
    for (int ct = 0; ct < 12; ct++)
#pragma unroll
      for (int r = 0; r < 4; r++)
        KQ[(w * 16 + quad * 4 + r) * 200 + ct * 16 + l15] = f2bf(qacc[ct][r] * SCALE);
  }
  __syncthreads();
  v8s qa[NHD];
#pragma unroll
  for (int h = 0; h < NHD; h++)
    qa[h] = *(const v8s*)(KQ + (w * 16 + l15) * 200 + h * 32 + quad * 8);
  __syncthreads();   // qa in registers; KQ free for K_j

  v4f acc[12];
#pragma unroll
  for (int ct = 0; ct < 12; ct++) acc[ct] = vzero;
  const float* xi = x + (size_t)(i * NB + b) * HWN * DIM;  // x.view reinterpretation

  for (int j = 0; j < TT; j++) {
    // ---- K_j, V_j from x (strips dead here; xp aliases them) ----
    stage_frame(j);
    __syncthreads();
    {
      v4f kacc[12], vacc[12];
#pragma unroll
      for (int ct = 0; ct < 12; ct++) { kacc[ct] = vzero; vacc[ct] = vzero; }
#pragma unroll
      for (int ks = 0; ks < 6; ks++) {
        v8s a = *(const v8s*)(xp + (w * 16 + l15) * 200 + ks * 32 + quad * 8);
#pragma unroll
        for (int ct = 0; ct < 12; ct++) {
          v8s bk = *(const v8s*)(Wqkv_bf + (size_t)(DIM + ct * 16 + l15) * DIM + ks * 32 + quad * 8);
          kacc[ct] = __builtin_amdgcn_mfma_f32_16x16x32_bf16(a, bk, kacc[ct], 0, 0, 0);
          v8s bv = *(const v8s*)(Wqkv_bf + (size_t)(2 * DIM + ct * 16 + l15) * DIM + ks * 32 + quad * 8);
          vacc[ct] = __builtin_amdgcn_mfma_f32_16x16x32_bf16(a, bv, vacc[ct], 0, 0, 0);
        }
      }
#pragma unroll
      for (int ct = 0; ct < 12; ct++) {
        int cc = ct * 16 + l15;
#pragma unroll
        for (int r = 0; r < 4; r++) {
          int row = w * 16 + quad * 4 + r;
          KQ[row * 200 + cc] = f2bf(kacc[ct][r]);
          Vt[cc * 72 + row]  = f2bf(vacc[ct][r]);
        }
      }
    }
    __syncthreads();

    // ---- attention heads: o rows w*16..+15 -> SX[w] ----
    for (int h = 0; h < NHD; h++) {
      v4f S[4];
#pragma unroll
      for (int ct = 0; ct < 4; ct++) {
        v8s kf = *(const v8s*)(KQ + (ct * 16 + l15) * 200 + h * 32 + quad * 8);
        S[ct] = __builtin_amdgcn_mfma_f32_16x16x32_bf16(qa[h], kf, vzero, 0, 0, 0);
      }
#pragma unroll
      for (int r = 0; r < 4; r++) {
        float mx = fmaxf(fmaxf(S[0][r], S[1][r]), fmaxf(S[2][r], S[3][r]));
#pragma unroll
        for (int off = 1; off < 16; off <<= 1) mx = fmaxf(mx, __shfl_xor(mx, off, 64));
        float sum = 0.f;
#pragma unroll
        for (int ct = 0; ct < 4; ct++) {
          float e = __expf(S[ct][r] - mx);
          S[ct][r] = e; sum += e;
        }
#pragma unroll
        for (int off = 1; off < 16; off <<= 1) sum += __shfl_xor(sum, off, 64);
        float inv = 1.0f / sum;
#pragma unroll
        for (int ct = 0; ct < 4; ct++)
          Pl[w][(quad * 4 + r) * 72 + ct * 16 + l15] = f2bf(S[ct][r] * inv);
      }
      __syncthreads();
      v8s pa0 = *(const v8s*)(&Pl[w][l15 * 72 + quad * 8]);
      v8s pa1 = *(const v8s*)(&Pl[w][l15 * 72 + 32 + quad * 8]);
#pragma unroll
      for (int ct2 = 0; ct2 < 2; ct2++) {
        v8s vf0 = *(const v8s*)(&Vt[(h * 32 + ct2 * 16 + l15) * 72 + quad * 8]);
        v8s vf1 = *(const v8s*)(&Vt[(h * 32 + ct2 * 16 + l15) * 72 + 32 + quad * 8]);
        v4f o = __builtin_amdgcn_mfma_f32_16x16x32_bf16(pa0, vf0, vzero, 0, 0, 0);
        o = __builtin_amdgcn_mfma_f32_16x16x32_bf16(pa1, vf1, o, 0, 0, 0);
#pragma unroll
        for (int r = 0; r < 4; r++)
          SX[w][(quad * 4 + r) * 200 + h * 32 + ct2 * 16 + l15] = f2bf(o[r]);
      }
      __syncthreads();
    }

    // ---- GEMM1: y1 = [o | x_i_view] @ Wproj^T ----
    v4f y1[12];
#pragma unroll
    for (int ct = 0; ct < 12; ct++) y1[ct] = vzero;
#pragma unroll
    for (int ks = 0; ks < 12; ks++) {
      v8s a;
      if (ks < 6) {
        a = *(const v8s*)(&SX[w][l15 * 200 + ks * 32 + quad * 8]);
      } else {
        const float* xs = xi + (size_t)(w * 16 + l15) * DIM + (ks - 6) * 32 + quad * 8;
#pragma unroll
        for (int jj = 0; jj < 8; jj++) a[jj] = f2bf(xs[jj]);
      }
#pragma unroll
      for (int ct = 0; ct < 12; ct++) {
        v8s bf = *(const v8s*)(Wproj_bf + (size_t)(ct * 16 + l15) * 384 + ks * 32 + quad * 8);
        y1[ct] = __builtin_amdgcn_mfma_f32_16x16x32_bf16(a, bf, y1[ct], 0, 0, 0);
      }
    }
#pragma unroll
    for (int ct = 0; ct < 12; ct++) {
      float bp = bproj[ct * 16 + l15];
#pragma unroll
      for (int r = 0; r < 4; r++) y1[ct][r] += bp;
    }
    float mu[4], rs[4];
#pragma unroll
    for (int r = 0; r < 4; r++) {
      float s1 = 0.f, s2 = 0.f;
#pragma unroll
      for (int ct = 0; ct < 12; ct++) { float v = y1[ct][r]; s1 += v; s2 += v * v; }
#pragma unroll
      for (int off = 1; off < 16; off <<= 1) { s1 += __shfl_xor(s1, off, 64); s2 += __shfl_xor(s2, off, 64); }
      float m = s1 * (1.0f / 192.0f);
      mu[r] = m; rs[r] = rsqrtf(s2 * (1.0f / 192.0f) - m * m + 1e-5f);
    }
    __syncthreads();   // GEMM1 strip reads done before overwrite
#pragma unroll
    for (int ct = 0; ct < 12; ct++) {
      int cc = ct * 16 + l15;
      float g = gamma[cc], be = beta[cc];
#pragma unroll
      for (int r = 0; r < 4; r++)
        SX[w][(quad * 4 + r) * 200 + cc] = f2bf((y1[ct][r] - mu[r]) * rs[r] * g + be);
    }
    __syncthreads();

    // ---- GEMM2: h = gelu(y1n @ W1^T + b1) ----
    v8s ha[6];
#pragma unroll
    for (int ks = 0; ks < 6; ks++) ha[ks] = *(const v8s*)(&SX[w][l15 * 200 + ks * 32 + quad * 8]);
    v4f y2[12];
#pragma unroll
    for (int ct = 0; ct < 12; ct++) y2[ct] = vzero;
#pragma unroll
    for (int ks = 0; ks < 6; ks++) {
#pragma unroll
      for (int ct = 0; ct < 12; ct++) {
        v8s bf = *(const v8s*)(W1_bf + (size_t)(ct * 16 + l15) * DIM + ks * 32 + quad * 8);
        y2[ct] = __builtin_amdgcn_mfma_f32_16x16x32_bf16(ha[ks], bf, y2[ct], 0, 0, 0);
      }
    }
    __syncthreads();
#pragma unroll
    for (int ct = 0; ct < 12; ct++) {
      float bb = b1[ct * 16 + l15];
#pragma unroll
      for (int r = 0; r < 4; r++) {
        float v = y2[ct][r] + bb;
        v = 0.5f * v * (1.0f + erff(v * 0.7071067811865475f));  // exact GELU
        SX[w][(quad * 4 + r) * 200 + ct * 16 + l15] = f2bf(v);
      }
    }
    __syncthreads();

    // ---- GEMM3: acc += h @ W2^T ----
#pragma unroll
    for (int ks = 0; ks < 6; ks++) ha[ks] = *(const v8s*)(&SX[w][l15 * 200 + ks * 32 + quad * 8]);
#pragma unroll
    for (int ks = 0; ks < 6; ks++) {
#pragma unroll
      for (int ct = 0; ct < 12; ct++) {
        v8s bf = *(const v8s*)(W2_bf + (size_t)(ct * 16 + l15) * DIM + ks * 32 + quad * 8);
        acc[ct] = __builtin_amdgcn_mfma_f32_16x16x32_bf16(ha[ks], bf, acc[ct], 0, 0, 0);
      }
    }
    __syncthreads();   // strip reads done; next j restages xp into SX
  }

  // ---- epilogue: out = [x | x + acc/6 + b2]  (fp32, x-half bit-exact) ----
#pragma unroll
  for (int ct = 0; ct < 12; ct++) {
    int cc = ct * 16 + l15;
    float b2v = b2[cc];
#pragma unroll
    for (int r = 0; r < 4; r++) {
      int hw = w * 16 + quad * 4 + r;
      size_t nrow = (size_t)b * 384 + (size_t)i * 64 + hw;
      float xs = x[nrow * DIM + cc];
      out[nrow * 384 + cc] = xs;
      out[nrow * 384 + 192 + cc] = xs + acc[ct][r] * (1.0f / 6.0f) + b2v;
    }
  }
}

extern "C" void kernel_launch(void* const* d_in, const int* in_sizes, int n_in,
                              void* d_out, int out_size, void* d_ws, size_t ws_size,
                              hipStream_t stream) {
  (void)in_sizes; (void)n_in; (void)out_size; (void)ws_size;
  const float* x     = (const float*)d_in[0];
  const float* Wqkv  = (const float*)d_in[1];
  const float* Wproj = (const float*)d_in[2];
  const float* bproj = (const float*)d_in[3];
  const float* gamma = (const float*)d_in[4];
  const float* beta  = (const float*)d_in[5];
  const float* W1    = (const float*)d_in[6];
  const float* b1    = (const float*)d_in[7];
  const float* W2    = (const float*)d_in[8];
  const float* b2    = (const float*)d_in[9];
  float* out = (float*)d_out;

  // ws: bf16 copies of the 4 weight matrices (516 KB total)
  short* Wqkv_bf  = (short*)d_ws;                 // 576*192 = 110592
  short* Wproj_bf = Wqkv_bf + 110592;             // 192*384 =  73728
  short* W1_bf    = Wproj_bf + 73728;             // 192*192 =  36864
  short* W2_bf    = W1_bf + 36864;                // 192*192 =  36864

  cvt_kernel<<<dim3((110592 / 4 + 255) / 256), dim3(256), 0, stream>>>(Wqkv, Wqkv_bf, 110592 / 4);
  cvt_kernel<<<dim3((73728 / 4 + 255) / 256), dim3(256), 0, stream>>>(Wproj, Wproj_bf, 73728 / 4);
  cvt_kernel<<<dim3((36864 / 4 + 255) / 256), dim3(256), 0, stream>>>(W1, W1_bf, 36864 / 4);
  cvt_kernel<<<dim3((36864 / 4 + 255) / 256), dim3(256), 0, stream>>>(W2, W2_bf, 36864 / 4);

  fused_all<<<dim3(TT, NB), dim3(256), 0, stream>>>(
      x, Wqkv_bf, Wproj_bf, W1_bf, W2_bf, bproj, gamma, beta, b1, b2, out);
}

// Round 5
// 1312.506 us; speedup vs baseline: 3.6468x; 3.6468x over previous
//
#include <hip/hip_runtime.h>
#include <cmath>

#define TT   6
#define NB   128
#define NHD  6
#define HD   32
#define HWN  64
#define DIM  192
#define SCALE 0.17677669529663687f

typedef __attribute__((ext_vector_type(8))) short v8s;
typedef __attribute__((ext_vector_type(4))) float v4f;

__device__ __forceinline__ short f2bf(float f) {
  union { float f; unsigned u; } v; v.f = f;
  unsigned r = v.u + 0x7fffu + ((v.u >> 16) & 1u);
  return (short)(r >> 16);
}

// ---- converter: fp32 -> bf16 weights ----
__global__ void cvt_kernel(const float* __restrict__ src, short* __restrict__ dst, int n4) {
  int idx = blockIdx.x * 256 + threadIdx.x;
  if (idx >= n4) return;
  const float* s = src + idx * 4;
  short4 r;
  r.x = f2bf(s[0]); r.y = f2bf(s[1]); r.z = f2bf(s[2]); r.w = f2bf(s[3]);
  *(short4*)(dst + idx * 4) = r;
}

// One block per (i, b). Weights staged per-chunk into LDS (Wb) shared by all 4
// waves; A-tiles per-wave. LDS ~130 KB -> 1 block/CU, 4 waves.
__global__ __launch_bounds__(256, 1) void fused_all(
    const float* __restrict__ x,
    const short* __restrict__ Wqkv_bf,
    const short* __restrict__ Wproj_bf,
    const short* __restrict__ W1_bf,
    const short* __restrict__ W2_bf,
    const float* __restrict__ bproj, const float* __restrict__ gamma,
    const float* __restrict__ beta, const float* __restrict__ b1,
    const float* __restrict__ b2,
    float* __restrict__ out) {
  __shared__ float posy[768];
  __shared__ float posx[768];
  __shared__ short KQ[64 * 200];     // Q_i then K_j rows (stride 200)
  __shared__ short Vt[DIM * 72];     // V_j^T (stride 72)
  __shared__ short SX[4][16 * 200];  // per-wave strip; block-wide (x+pos) staging
  __shared__ short Pl[4][16 * 72];   // per-wave P round-trip
  __shared__ short Wb[96 * 200];     // staged weight chunk: 96 N-rows x 192 K

  int i = blockIdx.x, b = blockIdx.y;
  int tid = threadIdx.x, w = tid >> 6, lane = tid & 63;
  int l15 = lane & 15, quad = lane >> 4;
  const v4f vzero = {0.f, 0.f, 0.f, 0.f};
  short* xp = &SX[0][0];

  // ---- sine position tables ----
  for (int idx = tid; idx < 1536; idx += 256) {
    int hx = idx / 768;
    int rem = idx - hx * 768;
    int rr = rem / 96, c = rem - rr * 96;
    int m = c >> 1;
    float embed = (float)(rr + 1) * (6.283185307179586f / 8.000001f);
    float dt = powf(10000.0f, (float)m * (1.0f / 48.0f));
    float ang = embed / dt;
    float v = (c & 1) ? cosf(ang) : sinf(ang);
    (hx ? posx : posy)[rr * 96 + c] = v;
  }
  __syncthreads();   // pos tables visible (r4 was racy-lucky here)

  auto stage_frame = [&](int t) {   // xp = bf16(x[b, frame t] + pos)
    const float* xrow = x + (size_t)(b * (TT * HWN) + t * HWN) * DIM;
    for (int c = tid; c < HWN * 24; c += 256) {
      int row = c / 24, col8 = (c - (c / 24) * 24) * 8;
      const float* xs = xrow + row * DIM + col8;
      const float* pp = (col8 < 96) ? (posy + (row >> 3) * 96 + col8)
                                    : (posx + (row & 7) * 96 + (col8 - 96));
      v8s r8;
#pragma unroll
      for (int jj = 0; jj < 8; jj++) r8[jj] = f2bf(xs[jj] + pp[jj]);
      *(v8s*)(xp + row * 200 + col8) = r8;
    }
  };

  auto stage_w = [&](const short* src, int rstride) {  // 96 rows x 192 -> Wb
    for (int c = tid; c < 96 * 24; c += 256) {
      int row = c / 24, col8 = (c - (c / 24) * 24) * 8;
      *(v8s*)(&Wb[row * 200 + col8]) = *(const v8s*)(src + (size_t)row * rstride + col8);
    }
  };

  const float* xi = x + (size_t)(i * NB + b) * HWN * DIM;  // x.view reinterpretation

  // ---- Q_i ----
  stage_frame(i);
  __syncthreads();
#pragma unroll
  for (int half = 0; half < 2; half++) {
    stage_w(Wqkv_bf + (size_t)(half * 96) * DIM, DIM);
    __syncthreads();
    v4f qacc[6];
#pragma unroll
    for (int ct = 0; ct < 6; ct++) qacc[ct] = vzero;
#pragma unroll
    for (int ks = 0; ks < 6; ks++) {
      v8s a = *(const v8s*)(xp + (w * 16 + l15) * 200 + ks * 32 + quad * 8);
#pragma unroll
      for (int ct = 0; ct < 6; ct++) {
        v8s bf = *(const v8s*)(&Wb[(ct * 16 + l15) * 200 + ks * 32 + quad * 8]);
        qacc[ct] = __builtin_amdgcn_mfma_f32_16x16x32_bf16(a, bf, qacc[ct], 0, 0, 0);
      }
    }
#pragma unroll
    for (int ct = 0; ct < 6; ct++)
#pragma unroll
      for (int r = 0; r < 4; r++)
        KQ[(w * 16 + quad * 4 + r) * 200 + half * 96 + ct * 16 + l15] = f2bf(qacc[ct][r] * SCALE);
    __syncthreads();
  }
  v8s qa[NHD];
#pragma unroll
  for (int h = 0; h < NHD; h++)
    qa[h] = *(const v8s*)(&KQ[(w * 16 + l15) * 200 + h * 32 + quad * 8]);
  v8s xia[6];   // xi A-fragments, bf16, reused across all j
  {
    const float* xr = xi + (size_t)(w * 16 + l15) * DIM;
#pragma unroll
    for (int ks = 0; ks < 6; ks++) {
      v8s a;
#pragma unroll
      for (int jj = 0; jj < 8; jj++) a[jj] = f2bf(xr[ks * 32 + quad * 8 + jj]);
      xia[ks] = a;
    }
  }

  v4f acc[12];
#pragma unroll
  for (int a = 0; a < 12; a++) acc[a] = vzero;

  for (int j = 0; j < TT; j++) {
    __syncthreads();             // qa/xia in regs; SX free for staging
    stage_frame(j);
    __syncthreads();
    // ---- K_j halves ----
#pragma unroll
    for (int half = 0; half < 2; half++) {
      stage_w(Wqkv_bf + (size_t)(DIM + half * 96) * DIM, DIM);
      __syncthreads();
      v4f kacc[6];
#pragma unroll
      for (int ct = 0; ct < 6; ct++) kacc[ct] = vzero;
#pragma unroll
      for (int ks = 0; ks < 6; ks++) {
        v8s a = *(const v8s*)(xp + (w * 16 + l15) * 200 + ks * 32 + quad * 8);
#pragma unroll
        for (int ct = 0; ct < 6; ct++) {
          v8s bf = *(const v8s*)(&Wb[(ct * 16 + l15) * 200 + ks * 32 + quad * 8]);
          kacc[ct] = __builtin_amdgcn_mfma_f32_16x16x32_bf16(a, bf, kacc[ct], 0, 0, 0);
        }
      }
#pragma unroll
      for (int ct = 0; ct < 6; ct++)
#pragma unroll
        for (int r = 0; r < 4; r++)
          KQ[(w * 16 + quad * 4 + r) * 200 + half * 96 + ct * 16 + l15] = f2bf(kacc[ct][r]);
      __syncthreads();
    }
    // ---- V_j halves ----
#pragma unroll
    for (int half = 0; half < 2; half++) {
      stage_w(Wqkv_bf + (size_t)(2 * DIM + half * 96) * DIM, DIM);
      __syncthreads();
      v4f vacc[6];
#pragma unroll
      for (int ct = 0; ct < 6; ct++) vacc[ct] = vzero;
#pragma unroll
      for (int ks = 0; ks < 6; ks++) {
        v8s a = *(const v8s*)(xp + (w * 16 + l15) * 200 + ks * 32 + quad * 8);
#pragma unroll
        for (int ct = 0; ct < 6; ct++) {
          v8s bf = *(const v8s*)(&Wb[(ct * 16 + l15) * 200 + ks * 32 + quad * 8]);
          vacc[ct] = __builtin_amdgcn_mfma_f32_16x16x32_bf16(a, bf, vacc[ct], 0, 0, 0);
        }
      }
#pragma unroll
      for (int ct = 0; ct < 6; ct++)
#pragma unroll
        for (int r = 0; r < 4; r++)
          Vt[(half * 96 + ct * 16 + l15) * 72 + w * 16 + quad * 4 + r] = f2bf(vacc[ct][r]);
      __syncthreads();
    }

    // ---- attention heads: o rows w*16..+15 -> SX[w] ----
    for (int h = 0; h < NHD; h++) {
      v4f S[4];
#pragma unroll
      for (int ct = 0; ct < 4; ct++) {
        v8s kf = *(const v8s*)(&KQ[(ct * 16 + l15) * 200 + h * 32 + quad * 8]);
        S[ct] = __builtin_amdgcn_mfma_f32_16x16x32_bf16(qa[h], kf, vzero, 0, 0, 0);
      }
#pragma unroll
      for (int r = 0; r < 4; r++) {
        float mx = fmaxf(fmaxf(S[0][r], S[1][r]), fmaxf(S[2][r], S[3][r]));
#pragma unroll
        for (int off = 1; off < 16; off <<= 1) mx = fmaxf(mx, __shfl_xor(mx, off, 64));
        float sum = 0.f;
#pragma unroll
        for (int ct = 0; ct < 4; ct++) {
          float e = __expf(S[ct][r] - mx);
          S[ct][r] = e; sum += e;
        }
#pragma unroll
        for (int off = 1; off < 16; off <<= 1) sum += __shfl_xor(sum, off, 64);
        float inv = 1.0f / sum;
#pragma unroll
        for (int ct = 0; ct < 4; ct++)
          Pl[w][(quad * 4 + r) * 72 + ct * 16 + l15] = f2bf(S[ct][r] * inv);
      }
      __syncthreads();
      v8s pa0 = *(const v8s*)(&Pl[w][l15 * 72 + quad * 8]);
      v8s pa1 = *(const v8s*)(&Pl[w][l15 * 72 + 32 + quad * 8]);
#pragma unroll
      for (int ct2 = 0; ct2 < 2; ct2++) {
        v8s vf0 = *(const v8s*)(&Vt[(h * 32 + ct2 * 16 + l15) * 72 + quad * 8]);
        v8s vf1 = *(const v8s*)(&Vt[(h * 32 + ct2 * 16 + l15) * 72 + 32 + quad * 8]);
        v4f o = __builtin_amdgcn_mfma_f32_16x16x32_bf16(pa0, vf0, vzero, 0, 0, 0);
        o = __builtin_amdgcn_mfma_f32_16x16x32_bf16(pa1, vf1, o, 0, 0, 0);
#pragma unroll
        for (int r = 0; r < 4; r++)
          SX[w][(quad * 4 + r) * 200 + h * 32 + ct2 * 16 + l15] = f2bf(o[r]);
      }
      __syncthreads();
    }

    // ---- GEMM1: y1 = [o | xi] @ Wproj^T, weights via Wb chunks ----
    v4f y1[12];
#pragma unroll
    for (int a = 0; a < 12; a++) y1[a] = vzero;
#pragma unroll
    for (int kc = 0; kc < 2; kc++) {
#pragma unroll
      for (int nh = 0; nh < 2; nh++) {
        stage_w(Wproj_bf + (size_t)(nh * 96) * 384 + kc * 192, 384);
        __syncthreads();
#pragma unroll
        for (int ks = 0; ks < 6; ks++) {
          v8s a = (kc == 0) ? *(const v8s*)(&SX[w][l15 * 200 + ks * 32 + quad * 8]) : xia[ks];
#pragma unroll
          for (int ct = 0; ct < 6; ct++) {
            v8s bf = *(const v8s*)(&Wb[(ct * 16 + l15) * 200 + ks * 32 + quad * 8]);
            y1[nh * 6 + ct] = __builtin_amdgcn_mfma_f32_16x16x32_bf16(a, bf, y1[nh * 6 + ct], 0, 0, 0);
          }
        }
        __syncthreads();
      }
    }
    // ---- +bproj, LayerNorm ----
#pragma unroll
    for (int a = 0; a < 12; a++) {
      int cc = (a / 6) * 96 + (a % 6) * 16 + l15;
      float bp = bproj[cc];
#pragma unroll
      for (int r = 0; r < 4; r++) y1[a][r] += bp;
    }
    float mu[4], rs[4];
#pragma unroll
    for (int r = 0; r < 4; r++) {
      float s1 = 0.f, s2 = 0.f;
#pragma unroll
      for (int a = 0; a < 12; a++) { float v = y1[a][r]; s1 += v; s2 += v * v; }
#pragma unroll
      for (int off = 1; off < 16; off <<= 1) { s1 += __shfl_xor(s1, off, 64); s2 += __shfl_xor(s2, off, 64); }
      float m = s1 * (1.0f / 192.0f);
      mu[r] = m; rs[r] = rsqrtf(s2 * (1.0f / 192.0f) - m * m + 1e-5f);
    }
#pragma unroll
    for (int a = 0; a < 12; a++) {
      int cc = (a / 6) * 96 + (a % 6) * 16 + l15;
      float g = gamma[cc], be = beta[cc];
#pragma unroll
      for (int r = 0; r < 4; r++)
        SX[w][(quad * 4 + r) * 200 + cc] = f2bf((y1[a][r] - mu[r]) * rs[r] * g + be);
    }

    // ---- GEMM2: y2 = y1n @ W1^T ----
    v4f y2[12];
#pragma unroll
    for (int a = 0; a < 12; a++) y2[a] = vzero;
#pragma unroll
    for (int nh = 0; nh < 2; nh++) {
      stage_w(W1_bf + (size_t)(nh * 96) * DIM, DIM);
      __syncthreads();
#pragma unroll
      for (int ks = 0; ks < 6; ks++) {
        v8s a = *(const v8s*)(&SX[w][l15 * 200 + ks * 32 + quad * 8]);
#pragma unroll
        for (int ct = 0; ct < 6; ct++) {
          v8s bf = *(const v8s*)(&Wb[(ct * 16 + l15) * 200 + ks * 32 + quad * 8]);
          y2[nh * 6 + ct] = __builtin_amdgcn_mfma_f32_16x16x32_bf16(a, bf, y2[nh * 6 + ct], 0, 0, 0);
        }
      }
      __syncthreads();
    }
    // ---- +b1, exact GELU -> SX[w] ----
#pragma unroll
    for (int a = 0; a < 12; a++) {
      int cc = (a / 6) * 96 + (a % 6) * 16 + l15;
      float bb = b1[cc];
#pragma unroll
      for (int r = 0; r < 4; r++) {
        float v = y2[a][r] + bb;
        v = 0.5f * v * (1.0f + erff(v * 0.7071067811865475f));
        SX[w][(quad * 4 + r) * 200 + cc] = f2bf(v);
      }
    }

    // ---- GEMM3: acc += h @ W2^T ----
#pragma unroll
    for (int nh = 0; nh < 2; nh++) {
      stage_w(W2_bf + (size_t)(nh * 96) * DIM, DIM);
      __syncthreads();
#pragma unroll
      for (int ks = 0; ks < 6; ks++) {
        v8s a = *(const v8s*)(&SX[w][l15 * 200 + ks * 32 + quad * 8]);
#pragma unroll
        for (int ct = 0; ct < 6; ct++) {
          v8s bf = *(const v8s*)(&Wb[(ct * 16 + l15) * 200 + ks * 32 + quad * 8]);
          acc[nh * 6 + ct] = __builtin_amdgcn_mfma_f32_16x16x32_bf16(a, bf, acc[nh * 6 + ct], 0, 0, 0);
        }
      }
      __syncthreads();
    }
  }

  // ---- epilogue: out = [x | x + acc/6 + b2] ----
#pragma unroll
  for (int a = 0; a < 12; a++) {
    int cc = (a / 6) * 96 + (a % 6) * 16 + l15;
    float b2v = b2[cc];
#pragma unroll
    for (int r = 0; r < 4; r++) {
      int hw = w * 16 + quad * 4 + r;
      size_t nrow = (size_t)b * 384 + (size_t)i * 64 + hw;
      float xs = x[nrow * DIM + cc];
      out[nrow * 384 + cc] = xs;
      out[nrow * 384 + 192 + cc] = xs + acc[a][r] * (1.0f / 6.0f) + b2v;
    }
  }
}

extern "C" void kernel_launch(void* const* d_in, const int* in_sizes, int n_in,
                              void* d_out, int out_size, void* d_ws, size_t ws_size,
                              hipStream_t stream) {
  (void)in_sizes; (void)n_in; (void)out_size; (void)ws_size;
  const float* x     = (const float*)d_in[0];
  const float* Wqkv  = (const float*)d_in[1];
  const float* Wproj = (const float*)d_in[2];
  const float* bproj = (const float*)d_in[3];
  const float* gamma = (const float*)d_in[4];
  const float* beta  = (const float*)d_in[5];
  const float* W1    = (const float*)d_in[6];
  const float* b1    = (const float*)d_in[7];
  const float* W2    = (const float*)d_in[8];
  const float* b2    = (const float*)d_in[9];
  float* out = (float*)d_out;

  short* Wqkv_bf  = (short*)d_ws;                 // 576*192
  short* Wproj_bf = Wqkv_bf + 110592;             // 192*384
  short* W1_bf    = Wproj_bf + 73728;             // 192*192
  short* W2_bf    = W1_bf + 36864;                // 192*192

  cvt_kernel<<<dim3(108), dim3(256), 0, stream>>>(Wqkv, Wqkv_bf, 110592 / 4);
  cvt_kernel<<<dim3(72), dim3(256), 0, stream>>>(Wproj, Wproj_bf, 73728 / 4);
  cvt_kernel<<<dim3(36), dim3(256), 0, stream>>>(W1, W1_bf, 36864 / 4);
  cvt_kernel<<<dim3(36), dim3(256), 0, stream>>>(W2, W2_bf, 36864 / 4);

  fused_all<<<dim3(TT, NB), dim3(256), 0, stream>>>(
      x, Wqkv_bf, Wproj_bf, W1_bf, W2_bf, bproj, gamma, beta, b1, b2, out);
}

// Round 6
// 805.939 us; speedup vs baseline: 5.9390x; 1.6285x over previous
//
#include <hip/hip_runtime.h>
#include <cmath>

#define TT   6
#define NB   128
#define NHD  6
#define DIM  192
#define SCALE 0.17677669529663687f

typedef __attribute__((ext_vector_type(8))) short v8s;
typedef __attribute__((ext_vector_type(4))) float v4f;

__device__ __forceinline__ short f2bf(float f) {
  union { float f; unsigned u; } v; v.f = f;
  unsigned r = v.u + 0x7fffu + ((v.u >> 16) & 1u);
  return (short)(r >> 16);
}
__device__ __forceinline__ void fence() {
  __asm__ volatile("s_waitcnt lgkmcnt(0)" ::: "memory");
}

// ---- fp32 -> bf16 weight converter ----
__global__ void cvt_kernel(const float* __restrict__ src, short* __restrict__ dst, int n4) {
  int idx = blockIdx.x * 256 + threadIdx.x;
  if (idx >= n4) return;
  const float* s = src + idx * 4;
  short4 r;
  r.x = f2bf(s[0]); r.y = f2bf(s[1]); r.z = f2bf(s[2]); r.w = f2bf(s[3]);
  *(short4*)(dst + idx * 4) = r;
}

// One block per (i,b). Transposed GEMMs: wave w owns channel-slice rows
// [w*48, w*48+48) of each weight matrix as register A-fragments; B-fragments
// are activation rows from LDS, one read reused across 3 ct x 4 nt MFMAs.
__global__ __launch_bounds__(256, 1) void fused_all(
    const float* __restrict__ x,
    const short* __restrict__ Wqkv_bf,
    const short* __restrict__ Wproj_bf,
    const short* __restrict__ W1_bf,
    const short* __restrict__ W2_bf,
    const float* __restrict__ bproj, const float* __restrict__ gamma,
    const float* __restrict__ beta, const float* __restrict__ b1,
    const float* __restrict__ b2,
    float* __restrict__ out) {
  __shared__ float posy[768];
  __shared__ float posx[768];
  __shared__ short KQ[64 * 200];     // Q rows, then K_j rows: [hw][ch]
  __shared__ short Vt[192 * 72];     // V_j^T: [ch][hw]
  __shared__ short SP[64 * 200];     // (x+pos) staging / o / y1n / h: [hw][ch]
  __shared__ short Xi[64 * 200];     // bf16 x-view rows: [hw][ch]
  __shared__ short Pl[4][16 * 72];   // per-wave P: [q][hw_k]
  __shared__ float LNp[64][4][2];    // LN partials: [hw][wave][s1,s2]

  int i = blockIdx.x, b = blockIdx.y;
  int tid = threadIdx.x, w = tid >> 6, lane = tid & 63;
  int l15 = lane & 15, quad = lane >> 4;
  int cb = w * 48;                   // wave's channel-slice base
  const v4f vzero = {0.f, 0.f, 0.f, 0.f};

  // ---- preload j-invariant weight A-fragments into registers ----
  v8s Wpf[3][6], W1f[3][6], W2f[3][6];
#pragma unroll
  for (int cti = 0; cti < 3; cti++) {
    int wr = cb + cti * 16 + l15;
#pragma unroll
    for (int ks = 0; ks < 6; ks++) {
      Wpf[cti][ks] = *(const v8s*)(Wproj_bf + (size_t)wr * 384 + ks * 32 + quad * 8);
      W1f[cti][ks] = *(const v8s*)(W1_bf + (size_t)wr * 192 + ks * 32 + quad * 8);
      W2f[cti][ks] = *(const v8s*)(W2_bf + (size_t)wr * 192 + ks * 32 + quad * 8);
    }
  }

  // ---- sine position tables ----
  for (int idx = tid; idx < 1536; idx += 256) {
    int hx = idx / 768;
    int rem = idx - hx * 768;
    int rr = rem / 96, c = rem - rr * 96;
    int m = c >> 1;
    float embed = (float)(rr + 1) * (6.283185307179586f / 8.000001f);
    float dt = powf(10000.0f, (float)m * (1.0f / 48.0f));
    float ang = embed / dt;
    float v = (c & 1) ? cosf(ang) : sinf(ang);
    (hx ? posx : posy)[rr * 96 + c] = v;
  }
  __syncthreads();

  auto stage_frame = [&](int t) {   // SP = bf16(x[b, frame t] + pos)
    const float* xrow = x + (size_t)(b * (TT * 64) + t * 64) * DIM;
    for (int c = tid; c < 64 * 24; c += 256) {
      int row = c / 24, col8 = (c - (c / 24) * 24) * 8;
      const float* xs = xrow + row * DIM + col8;
      const float* pp = (col8 < 96) ? (posy + (row >> 3) * 96 + col8)
                                    : (posx + (row & 7) * 96 + (col8 - 96));
      v8s r8;
#pragma unroll
      for (int jj = 0; jj < 8; jj++) r8[jj] = f2bf(xs[jj] + pp[jj]);
      *(v8s*)(SP + row * 200 + col8) = r8;
    }
  };

  const float* xi = x + (size_t)(i * NB + b) * 64 * DIM;  // x.view reinterpretation

  // ---- stage frame i and Xi ----
  stage_frame(i);
  for (int c = tid; c < 64 * 24; c += 256) {
    int row = c / 24, col8 = (c - (c / 24) * 24) * 8;
    const float* xs = xi + row * DIM + col8;
    v8s r8;
#pragma unroll
    for (int jj = 0; jj < 8; jj++) r8[jj] = f2bf(xs[jj]);
    *(v8s*)(Xi + row * 200 + col8) = r8;
  }
  __syncthreads();

  // ---- Q^T = Wq · xp^T  (ct-sliced; A streamed from global) ----
  {
    v4f qacc[3][4];
#pragma unroll
    for (int cti = 0; cti < 3; cti++)
#pragma unroll
      for (int nt = 0; nt < 4; nt++) qacc[cti][nt] = vzero;
#pragma unroll
    for (int ks = 0; ks < 6; ks++) {
      v8s bq[4];
#pragma unroll
      for (int nt = 0; nt < 4; nt++)
        bq[nt] = *(const v8s*)(SP + (nt * 16 + l15) * 200 + ks * 32 + quad * 8);
#pragma unroll
      for (int cti = 0; cti < 3; cti++) {
        v8s aq = *(const v8s*)(Wqkv_bf + (size_t)(cb + cti * 16 + l15) * 192 + ks * 32 + quad * 8);
#pragma unroll
        for (int nt = 0; nt < 4; nt++)
          qacc[cti][nt] = __builtin_amdgcn_mfma_f32_16x16x32_bf16(aq, bq[nt], qacc[cti][nt], 0, 0, 0);
      }
    }
#pragma unroll
    for (int cti = 0; cti < 3; cti++)
#pragma unroll
      for (int nt = 0; nt < 4; nt++) {
        short4 s;
        s.x = f2bf(qacc[cti][nt][0] * SCALE); s.y = f2bf(qacc[cti][nt][1] * SCALE);
        s.z = f2bf(qacc[cti][nt][2] * SCALE); s.w = f2bf(qacc[cti][nt][3] * SCALE);
        *(short4*)(&KQ[(nt * 16 + l15) * 200 + cb + cti * 16 + quad * 4]) = s;
      }
  }
  __syncthreads();
  v8s qa[NHD];
#pragma unroll
  for (int h = 0; h < NHD; h++)
    qa[h] = *(const v8s*)(&KQ[(w * 16 + l15) * 200 + h * 32 + quad * 8]);

  v4f acc[3][4];
#pragma unroll
  for (int cti = 0; cti < 3; cti++)
#pragma unroll
    for (int nt = 0; nt < 4; nt++) acc[cti][nt] = vzero;

  for (int j = 0; j < TT; j++) {
    __syncthreads();               // prior strip/KQ/Vt reads done (and qa loads at j=0)
    stage_frame(j);
    __syncthreads();

    // ---- K^T, V^T = W{k,v} · xp^T (fused ks-loop, shared B-frags) ----
    {
      v4f kacc[3][4], vacc[3][4];
#pragma unroll
      for (int cti = 0; cti < 3; cti++)
#pragma unroll
        for (int nt = 0; nt < 4; nt++) { kacc[cti][nt] = vzero; vacc[cti][nt] = vzero; }
#pragma unroll
      for (int ks = 0; ks < 6; ks++) {
        v8s bx[4];
#pragma unroll
        for (int nt = 0; nt < 4; nt++)
          bx[nt] = *(const v8s*)(SP + (nt * 16 + l15) * 200 + ks * 32 + quad * 8);
#pragma unroll
        for (int cti = 0; cti < 3; cti++) {
          v8s ak = *(const v8s*)(Wqkv_bf + (size_t)(192 + cb + cti * 16 + l15) * 192 + ks * 32 + quad * 8);
          v8s av = *(const v8s*)(Wqkv_bf + (size_t)(384 + cb + cti * 16 + l15) * 192 + ks * 32 + quad * 8);
#pragma unroll
          for (int nt = 0; nt < 4; nt++) {
            kacc[cti][nt] = __builtin_amdgcn_mfma_f32_16x16x32_bf16(ak, bx[nt], kacc[cti][nt], 0, 0, 0);
            vacc[cti][nt] = __builtin_amdgcn_mfma_f32_16x16x32_bf16(av, bx[nt], vacc[cti][nt], 0, 0, 0);
          }
        }
      }
#pragma unroll
      for (int cti = 0; cti < 3; cti++)
#pragma unroll
        for (int nt = 0; nt < 4; nt++) {
          short4 s;
          s.x = f2bf(kacc[cti][nt][0]); s.y = f2bf(kacc[cti][nt][1]);
          s.z = f2bf(kacc[cti][nt][2]); s.w = f2bf(kacc[cti][nt][3]);
          *(short4*)(&KQ[(nt * 16 + l15) * 200 + cb + cti * 16 + quad * 4]) = s;
          int hw = nt * 16 + l15;
#pragma unroll
          for (int r = 0; r < 4; r++)
            Vt[(cb + cti * 16 + quad * 4 + r) * 72 + hw] = f2bf(vacc[cti][nt][r]);
        }
    }
    __syncthreads();

    // ---- attention (hw-sliced: wave w = q-rows w*16..+15) ----
    for (int h = 0; h < NHD; h++) {
      v4f S[4];
#pragma unroll
      for (int cta = 0; cta < 4; cta++) {
        v8s akq = *(const v8s*)(&KQ[(cta * 16 + l15) * 200 + h * 32 + quad * 8]);
        S[cta] = __builtin_amdgcn_mfma_f32_16x16x32_bf16(akq, qa[h], vzero, 0, 0, 0);
      }
      // per-lane 16 hw_k values for q-row l15; reduce across quads
      float mx = -1e30f;
#pragma unroll
      for (int cta = 0; cta < 4; cta++)
#pragma unroll
        for (int r = 0; r < 4; r++) mx = fmaxf(mx, S[cta][r]);
      mx = fmaxf(mx, __shfl_xor(mx, 16, 64));
      mx = fmaxf(mx, __shfl_xor(mx, 32, 64));
      float sum = 0.f;
#pragma unroll
      for (int cta = 0; cta < 4; cta++)
#pragma unroll
        for (int r = 0; r < 4; r++) {
          float e = __expf(S[cta][r] - mx);
          S[cta][r] = e; sum += e;
        }
      sum += __shfl_xor(sum, 16, 64);
      sum += __shfl_xor(sum, 32, 64);
      float inv = 1.0f / sum;
#pragma unroll
      for (int cta = 0; cta < 4; cta++) {
        short4 s;
        s.x = f2bf(S[cta][0] * inv); s.y = f2bf(S[cta][1] * inv);
        s.z = f2bf(S[cta][2] * inv); s.w = f2bf(S[cta][3] * inv);
        *(short4*)(&Pl[w][l15 * 72 + cta * 16 + quad * 4]) = s;
      }
      fence();
      v8s bp0 = *(const v8s*)(&Pl[w][l15 * 72 + quad * 8]);
      v8s bp1 = *(const v8s*)(&Pl[w][l15 * 72 + 32 + quad * 8]);
#pragma unroll
      for (int ct2 = 0; ct2 < 2; ct2++) {
        v8s av0 = *(const v8s*)(&Vt[(h * 32 + ct2 * 16 + l15) * 72 + quad * 8]);
        v8s av1 = *(const v8s*)(&Vt[(h * 32 + ct2 * 16 + l15) * 72 + 32 + quad * 8]);
        v4f o = __builtin_amdgcn_mfma_f32_16x16x32_bf16(av0, bp0, vzero, 0, 0, 0);
        o = __builtin_amdgcn_mfma_f32_16x16x32_bf16(av1, bp1, o, 0, 0, 0);
        short4 s;
        s.x = f2bf(o[0]); s.y = f2bf(o[1]); s.z = f2bf(o[2]); s.w = f2bf(o[3]);
        *(short4*)(&SP[(w * 16 + l15) * 200 + h * 32 + ct2 * 16 + quad * 4]) = s;
      }
      fence();
    }
    __syncthreads();

    // ---- G1: y1^T = Wproj · [o | xi]^T ----
    v4f y1[3][4];
#pragma unroll
    for (int cti = 0; cti < 3; cti++)
#pragma unroll
      for (int nt = 0; nt < 4; nt++) y1[cti][nt] = vzero;
#pragma unroll
    for (int ks = 0; ks < 6; ks++) {
      v8s bo[4];
#pragma unroll
      for (int nt = 0; nt < 4; nt++)
        bo[nt] = *(const v8s*)(SP + (nt * 16 + l15) * 200 + ks * 32 + quad * 8);
#pragma unroll
      for (int cti = 0; cti < 3; cti++)
#pragma unroll
        for (int nt = 0; nt < 4; nt++)
          y1[cti][nt] = __builtin_amdgcn_mfma_f32_16x16x32_bf16(Wpf[cti][ks], bo[nt], y1[cti][nt], 0, 0, 0);
    }
#pragma unroll
    for (int ks = 0; ks < 6; ks++) {
      v8s bxi[4];
#pragma unroll
      for (int nt = 0; nt < 4; nt++)
        bxi[nt] = *(const v8s*)(Xi + (nt * 16 + l15) * 200 + ks * 32 + quad * 8);
#pragma unroll
      for (int cti = 0; cti < 3; cti++) {
        v8s a = *(const v8s*)(Wproj_bf + (size_t)(cb + cti * 16 + l15) * 384 + 192 + ks * 32 + quad * 8);
#pragma unroll
        for (int nt = 0; nt < 4; nt++)
          y1[cti][nt] = __builtin_amdgcn_mfma_f32_16x16x32_bf16(a, bxi[nt], y1[cti][nt], 0, 0, 0);
      }
    }
    // + bproj; LN partials (wave covers 48 of 192 channels)
#pragma unroll
    for (int cti = 0; cti < 3; cti++) {
      float4 bp4 = *(const float4*)(bproj + cb + cti * 16 + quad * 4);
#pragma unroll
      for (int nt = 0; nt < 4; nt++) {
        y1[cti][nt][0] += bp4.x; y1[cti][nt][1] += bp4.y;
        y1[cti][nt][2] += bp4.z; y1[cti][nt][3] += bp4.w;
      }
    }
#pragma unroll
    for (int nt = 0; nt < 4; nt++) {
      float s1 = 0.f, s2 = 0.f;
#pragma unroll
      for (int cti = 0; cti < 3; cti++)
#pragma unroll
        for (int r = 0; r < 4; r++) { float v = y1[cti][nt][r]; s1 += v; s2 += v * v; }
      s1 += __shfl_xor(s1, 16, 64); s2 += __shfl_xor(s2, 16, 64);
      s1 += __shfl_xor(s1, 32, 64); s2 += __shfl_xor(s2, 32, 64);
      if (quad == 0) { LNp[nt * 16 + l15][w][0] = s1; LNp[nt * 16 + l15][w][1] = s2; }
    }
    __syncthreads();               // partials visible; all G1 strip reads done
    float mu[4], rs[4];
#pragma unroll
    for (int nt = 0; nt < 4; nt++) {
      float s1 = 0.f, s2 = 0.f;
#pragma unroll
      for (int ww = 0; ww < 4; ww++) {
        s1 += LNp[nt * 16 + l15][ww][0];
        s2 += LNp[nt * 16 + l15][ww][1];
      }
      float m = s1 * (1.0f / 192.0f);
      mu[nt] = m; rs[nt] = rsqrtf(s2 * (1.0f / 192.0f) - m * m + 1e-5f);
    }
#pragma unroll
    for (int cti = 0; cti < 3; cti++) {
      float4 g4 = *(const float4*)(gamma + cb + cti * 16 + quad * 4);
      float4 be4 = *(const float4*)(beta + cb + cti * 16 + quad * 4);
#pragma unroll
      for (int nt = 0; nt < 4; nt++) {
        short4 s;
        s.x = f2bf((y1[cti][nt][0] - mu[nt]) * rs[nt] * g4.x + be4.x);
        s.y = f2bf((y1[cti][nt][1] - mu[nt]) * rs[nt] * g4.y + be4.y);
        s.z = f2bf((y1[cti][nt][2] - mu[nt]) * rs[nt] * g4.z + be4.z);
        s.w = f2bf((y1[cti][nt][3] - mu[nt]) * rs[nt] * g4.w + be4.w);
        *(short4*)(&SP[(nt * 16 + l15) * 200 + cb + cti * 16 + quad * 4]) = s;
      }
    }
    __syncthreads();

    // ---- G2: y2^T = W1 · y1n^T ----
    v4f y2[3][4];
#pragma unroll
    for (int cti = 0; cti < 3; cti++)
#pragma unroll
      for (int nt = 0; nt < 4; nt++) y2[cti][nt] = vzero;
#pragma unroll
    for (int ks = 0; ks < 6; ks++) {
      v8s bh[4];
#pragma unroll
      for (int nt = 0; nt < 4; nt++)
        bh[nt] = *(const v8s*)(SP + (nt * 16 + l15) * 200 + ks * 32 + quad * 8);
#pragma unroll
      for (int cti = 0; cti < 3; cti++)
#pragma unroll
        for (int nt = 0; nt < 4; nt++)
          y2[cti][nt] = __builtin_amdgcn_mfma_f32_16x16x32_bf16(W1f[cti][ks], bh[nt], y2[cti][nt], 0, 0, 0);
    }
    __syncthreads();               // all G2 strip reads done before h overwrite
#pragma unroll
    for (int cti = 0; cti < 3; cti++) {
      float4 b14 = *(const float4*)(b1 + cb + cti * 16 + quad * 4);
#pragma unroll
      for (int nt = 0; nt < 4; nt++) {
        short4 s;
        float vv[4] = {y2[cti][nt][0] + b14.x, y2[cti][nt][1] + b14.y,
                       y2[cti][nt][2] + b14.z, y2[cti][nt][3] + b14.w};
        short sv[4];
#pragma unroll
        for (int r = 0; r < 4; r++) {
          float v = vv[r];
          float t = 0.79788456080286536f * (v + 0.044715f * v * v * v);
          float e = __expf(2.0f * t);
          float th = 1.0f - 2.0f / (e + 1.0f);
          sv[r] = f2bf(0.5f * v * (1.0f + th));
        }
        s.x = sv[0]; s.y = sv[1]; s.z = sv[2]; s.w = sv[3];
        *(short4*)(&SP[(nt * 16 + l15) * 200 + cb + cti * 16 + quad * 4]) = s;
      }
    }
    __syncthreads();

    // ---- G3: acc^T += W2 · h^T ----
#pragma unroll
    for (int ks = 0; ks < 6; ks++) {
      v8s bh[4];
#pragma unroll
      for (int nt = 0; nt < 4; nt++)
        bh[nt] = *(const v8s*)(SP + (nt * 16 + l15) * 200 + ks * 32 + quad * 8);
#pragma unroll
      for (int cti = 0; cti < 3; cti++)
#pragma unroll
        for (int nt = 0; nt < 4; nt++)
          acc[cti][nt] = __builtin_amdgcn_mfma_f32_16x16x32_bf16(W2f[cti][ks], bh[nt], acc[cti][nt], 0, 0, 0);
    }
  }

  // ---- epilogue: out = [x | x + acc/6 + b2] ----
#pragma unroll
  for (int cti = 0; cti < 3; cti++) {
    int cc0 = cb + cti * 16 + quad * 4;
    float4 b24 = *(const float4*)(b2 + cc0);
#pragma unroll
    for (int nt = 0; nt < 4; nt++) {
      int hw = nt * 16 + l15;
      size_t nrow = (size_t)b * 384 + (size_t)i * 64 + hw;
      float4 xv = *(const float4*)(x + nrow * DIM + cc0);
      float4 o4;
      o4.x = xv.x + acc[cti][nt][0] * (1.0f / 6.0f) + b24.x;
      o4.y = xv.y + acc[cti][nt][1] * (1.0f / 6.0f) + b24.y;
      o4.z = xv.z + acc[cti][nt][2] * (1.0f / 6.0f) + b24.z;
      o4.w = xv.w + acc[cti][nt][3] * (1.0f / 6.0f) + b24.w;
      *(float4*)(out + nrow * 384 + 192 + cc0) = o4;
    }
  }
  // x-half bit-exact copy
  for (int c = tid; c < 64 * 48; c += 256) {
    int row = c / 48, col4 = (c - (c / 48) * 48) * 4;
    size_t nrow = (size_t)b * 384 + (size_t)i * 64 + row;
    *(float4*)(out + nrow * 384 + col4) = *(const float4*)(x + nrow * DIM + col4);
  }
}

extern "C" void kernel_launch(void* const* d_in, const int* in_sizes, int n_in,
                              void* d_out, int out_size, void* d_ws, size_t ws_size,
                              hipStream_t stream) {
  (void)in_sizes; (void)n_in; (void)out_size; (void)ws_size;
  const float* x     = (const float*)d_in[0];
  const float* Wqkv  = (const float*)d_in[1];
  const float* Wproj = (const float*)d_in[2];
  const float* bproj = (const float*)d_in[3];
  const float* gamma = (const float*)d_in[4];
  const float* beta  = (const float*)d_in[5];
  const float* W1    = (const float*)d_in[6];
  const float* b1    = (const float*)d_in[7];
  const float* W2    = (const float*)d_in[8];
  const float* b2    = (const float*)d_in[9];
  float* out = (float*)d_out;

  short* Wqkv_bf  = (short*)d_ws;                 // 576*192
  short* Wproj_bf = Wqkv_bf + 110592;             // 192*384
  short* W1_bf    = Wproj_bf + 73728;             // 192*192
  short* W2_bf    = W1_bf + 36864;                // 192*192

  cvt_kernel<<<dim3(108), dim3(256), 0, stream>>>(Wqkv, Wqkv_bf, 110592 / 4);
  cvt_kernel<<<dim3(72), dim3(256), 0, stream>>>(Wproj, Wproj_bf, 73728 / 4);
  cvt_kernel<<<dim3(36), dim3(256), 0, stream>>>(W1, W1_bf, 36864 / 4);
  cvt_kernel<<<dim3(36), dim3(256), 0, stream>>>(W2, W2_bf, 36864 / 4);

  fused_all<<<dim3(TT, NB), dim3(256), 0, stream>>>(
      x, Wqkv_bf, Wproj_bf, W1_bf, W2_bf, bproj, gamma, beta, b1, b2, out);
}